// Round 9
// baseline (727.559 us; speedup 1.0000x reference)
//
#include <hip/hip_runtime.h>
#include <hip/hip_cooperative_groups.h>
#include <math.h>

#define B    4
#define T    16384
#define A    256
#define K    256
#define PAD  128
#define TP   (T + 2*PAD)      // 16640
#define TOUT (TP - K + 1)     // 16385
#define ITERS 16
#define CHUNK 512
#define NCHUNK 33
#define NCP  36               // padded per-atom chunk stride
#define TILE 2048
#define NTILE 9
#define NBLK 512              // grid: 128 blocks per batch, block owns atoms (2a0, 2a0+1)
#define BTH  512              // threads per block (8 waves)
#define NBB  128              // blocks per batch

struct Smem {
    float rp[2336];           // 580 quads staged window/tile
    float dnAB[2*K];          // own two atoms, contiguous
    float dnsel[K];           // picked atom
    float wv[16]; int wi[16];
    float fv; int fi;
};

#define TAP(acc, s0,s1,s2,s3, dq) { acc = fmaf(s0,(dq).x,acc); acc = fmaf(s1,(dq).y,acc); \
                                    acc = fmaf(s2,(dq).z,acc); acc = fmaf(s3,(dq).w,acc); }

__device__ __forceinline__ void wave_amax(float& bv, int& bi) {
    #pragma unroll
    for (int off = 32; off; off >>= 1) {
        float ov = __shfl_down(bv, off);
        int   oi = __shfl_down(bi, off);
        if (ov > bv || (ov == bv && oi < bi)) { bv = ov; bi = oi; }
    }
}

// Per-batch grid barrier (fan-in 128). Safe only under cooperative launch.
__device__ __forceinline__ void gbar(unsigned* c, unsigned target) {
    __syncthreads();
    if (threadIdx.x == 0) {
        __hip_atomic_fetch_add(c, 1u, __ATOMIC_RELEASE, __HIP_MEMORY_SCOPE_AGENT);
        while (__hip_atomic_load(c, __ATOMIC_ACQUIRE, __HIP_MEMORY_SCOPE_AGENT) < target)
            __builtin_amdgcn_s_sleep(2);
    }
    __syncthreads();
}

// ---------- norm (each batch writes dn redundantly - identical values) + init ----------
__device__ __forceinline__ void dev_norm_init(int a0, int b, int tid,
                                              const float* __restrict__ x,
                                              const float* __restrict__ d,
                                              float* __restrict__ dn,
                                              float* __restrict__ rp,
                                              float* __restrict__ recon, Smem& sm) {
    int lane = tid & 63, w = tid >> 6;
    int half = tid >> 8, k = tid & 255;
    int atom = a0*2 + half;
    float v = d[atom*K + k];
    float sq = v*v;
    #pragma unroll
    for (int off = 32; off; off >>= 1) sq += __shfl_down(sq, off);
    if (lane == 0) sm.wv[w] = sq;
    __syncthreads();
    float norm = sqrtf(sm.wv[half*4] + sm.wv[half*4+1] + sm.wv[half*4+2] + sm.wv[half*4+3]) + 1e-12f;
    dn[atom*K + k] = v / norm;
    __syncthreads();
    for (int i = a0*BTH + tid; i < TP; i += NBB*BTH) {
        float xv = (i >= PAD && i < PAD + T) ? x[b*T + (i - PAD)] : 0.f;
        rp[(size_t)b*TP + i] = xv;
        recon[(size_t)b*TP + i] = 0.f;
    }
}

// ---------- full conv for 2 atoms, TM=4 per thread, chunk maxima -> segval ----------
__device__ void dev_conv(int a0, int b, int tid, const float* __restrict__ rp,
                         const float* __restrict__ dn,
                         float* __restrict__ segval, int* __restrict__ segidx,
                         float* __restrict__ abv, int* __restrict__ abi, Smem& sm) {
    const int aA = a0*2, aB = aA + 1;
    const int lane = tid & 63, w = tid >> 6;
    sm.dnAB[tid] = dn[aA*K + tid];                 // 512 floats = both atoms
    const float4* rp4 = (const float4*)(rp + (size_t)b*TP);

    for (int tile = 0; tile < NTILE; tile++) {
        int t0 = tile * TILE;
        __syncthreads();
        float4* s4 = (float4*)sm.rp;
        for (int i = tid; i < 580; i += BTH) {
            int g = t0/4 + i;
            float4 v = {0.f,0.f,0.f,0.f};
            if (g*4 < TP) v = rp4[g];
            s4[i] = v;
        }
        __syncthreads();
        const float4* srp4 = (const float4*)sm.rp;
        const float4* dA4  = (const float4*)sm.dnAB;
        const float4* dB4  = dA4 + 64;
        float accA[4] = {0,0,0,0}, accB[4] = {0,0,0,0};
        float4 p = srp4[tid];
        #pragma unroll 4
        for (int kq = 0; kq < 64; kq++) {
            float4 dA = dA4[kq];
            float4 dB = dB4[kq];
            float4 pn = srp4[tid + kq + 1];
            TAP(accA[0], p.x,p.y,p.z,p.w, dA); TAP(accA[1], p.y,p.z,p.w,pn.x, dA);
            TAP(accA[2], p.z,p.w,pn.x,pn.y, dA); TAP(accA[3], p.w,pn.x,pn.y,pn.z, dA);
            TAP(accB[0], p.x,p.y,p.z,p.w, dB); TAP(accB[1], p.y,p.z,p.w,pn.x, dB);
            TAP(accB[2], p.z,p.w,pn.x,pn.y, dB); TAP(accB[3], p.w,pn.x,pn.y,pn.z, dB);
            p = pn;
        }
        int lt = tid * 4;
        float bvA = -INFINITY, bvB = -INFINITY;
        int biA = 0x7fffffff, biB = 0x7fffffff;
        #pragma unroll
        for (int j = 0; j < 4; j++) {
            int t = t0 + lt + j;
            if (t < TOUT) {
                if (accA[j] > bvA) { bvA = accA[j]; biA = aA*TOUT + t; }
                if (accB[j] > bvB) { bvB = accB[j]; biB = aB*TOUT + t; }
            }
        }
        wave_amax(bvA, biA); wave_amax(bvB, biB);
        if (lane == 0) { sm.wv[w] = bvA; sm.wi[w] = biA; sm.wv[8+w] = bvB; sm.wi[8+w] = biB; }
        __syncthreads();
        // chunk c in tile (0..3): waves 2c, 2c+1
        if (tid < 4) {
            float v0 = sm.wv[2*tid];   int i0 = sm.wi[2*tid];
            float v1 = sm.wv[2*tid+1]; int i1 = sm.wi[2*tid+1];
            if (v1 > v0 || (v1 == v0 && i1 < i0)) { v0 = v1; i0 = i1; }
            int chunk = tile*4 + tid;
            if (chunk < NCHUNK) {
                segval[((size_t)b*A + aA)*NCP + chunk] = v0;
                segidx[((size_t)b*A + aA)*NCP + chunk] = i0;
            }
        } else if (tid >= 64 && tid < 68) {
            int c = tid - 64;
            float v0 = sm.wv[8+2*c];   int i0 = sm.wi[8+2*c];
            float v1 = sm.wv[8+2*c+1]; int i1 = sm.wi[8+2*c+1];
            if (v1 > v0 || (v1 == v0 && i1 < i0)) { v0 = v1; i0 = i1; }
            int chunk = tile*4 + c;
            if (chunk < NCHUNK) {
                segval[((size_t)b*A + aB)*NCP + chunk] = v0;
                segidx[((size_t)b*A + aB)*NCP + chunk] = i0;
            }
        }
    }
    __syncthreads();
    if (w < 2) {     // wave0 -> atom A, wave1 -> atom B
        int atom = (w == 0) ? aA : aB;
        float bv = -INFINITY; int bi = 0x7fffffff;
        if (lane < NCHUNK) {
            bv = segval[((size_t)b*A + atom)*NCP + lane];
            bi = segidx[((size_t)b*A + atom)*NCP + lane];
        }
        wave_amax(bv, bi);
        if (lane == 0) { abv[b*A + atom] = bv; abi[b*A + atom] = bi; }
    }
}

// ---------- one matching-pursuit iteration ----------
__device__ void dev_iter(int a0, int b, int tid, int last,
                         const float* __restrict__ avc, const int* __restrict__ aic,
                         float* __restrict__ avn, int* __restrict__ ain,
                         const float* __restrict__ rin, float* __restrict__ rout,
                         float* __restrict__ recon, const float* __restrict__ dn,
                         float* __restrict__ segval, int* __restrict__ segidx, Smem& sm) {
    const int aA = a0*2, aB = aA + 1;
    const int lane = tid & 63, w = tid >> 6;
    // pick (redundant, deterministic across blocks of same b)
    {
        float bv = avc[b*A + (tid & 255)];
        int   bi = aic[b*A + (tid & 255)];
        wave_amax(bv, bi);
        if (lane == 0) { sm.wv[w] = bv; sm.wi[w] = bi; }
        __syncthreads();
        if (tid == 0) {
            bv = sm.wv[0]; bi = sm.wi[0];
            for (int j = 1; j < 8; j++)
                if (sm.wv[j] > bv || (sm.wv[j] == bv && sm.wi[j] < bi)) { bv = sm.wv[j]; bi = sm.wi[j]; }
            sm.fv = bv; sm.fi = bi;
        }
        __syncthreads();
    }
    float val = sm.fv; int idx = sm.fi;
    int atom = idx / TOUT, pos = idx - atom*TOUT;
    if (tid < K) sm.dnsel[tid] = dn[atom*K + tid];
    sm.dnAB[tid] = dn[aA*K + tid];

    int lo = pos - (K-1); if (lo < 0) lo = 0;
    int c_base = (lo >> 9) & ~1;          // 2-chunk-aligned; dirty chunks within [c_base, c_base+4)
    int tbase = c_base * CHUNK;

    if (!last) {   // stage 4-chunk window [tbase, tbase+2320)
        const float4* rin4 = (const float4*)(rin + (size_t)b*TP);
        float4* s4 = (float4*)sm.rp;
        for (int i = tid; i < 580; i += BTH) {
            int g = tbase/4 + i;
            float4 v = {0.f,0.f,0.f,0.f};
            if (g*4 < TP) v = rin4[g];
            s4[i] = v;
        }
    }
    __syncthreads();
    if (!last) {   // distributed rp copy+update: 4160 quads over blocks a0=0..8
        const float4* rin4 = (const float4*)(rin + (size_t)b*TP);
        float4* rout4 = (float4*)(rout + (size_t)b*TP);
        int i = a0*BTH + tid;
        if (i < TP/4) {
            float4 v = rin4[i];
            int o = i*4 - pos;
            if (o > -4 && o < K) {
                if (o+0 >= 0 && o+0 < K) v.x -= val * sm.dnsel[o+0];
                if (o+1 >= 0 && o+1 < K) v.y -= val * sm.dnsel[o+1];
                if (o+2 >= 0 && o+2 < K) v.z -= val * sm.dnsel[o+2];
                if (o+3 >= 0 && o+3 < K) v.w -= val * sm.dnsel[o+3];
            }
            rout4[i] = v;
        }
    }
    if (a0 == 0 && tid < K) recon[(size_t)b*TP + pos + tid] += val * sm.dnsel[tid];
    if (last) return;

    // apply update delta in LDS (changed region [pos, pos+K) is inside the window)
    if (tid < K) sm.rp[pos - tbase + tid] -= val * sm.dnsel[tid];
    __syncthreads();

    // recompute 2048 outputs [tbase, tbase+2048) for both atoms (conv-identical chain)
    const float4* srp4 = (const float4*)sm.rp;
    const float4* dA4  = (const float4*)sm.dnAB;
    const float4* dB4  = dA4 + 64;
    float accA[4] = {0,0,0,0}, accB[4] = {0,0,0,0};
    float4 p = srp4[tid];
    #pragma unroll 4
    for (int kq = 0; kq < 64; kq++) {
        float4 dA = dA4[kq];
        float4 dB = dB4[kq];
        float4 pn = srp4[tid + kq + 1];
        TAP(accA[0], p.x,p.y,p.z,p.w, dA); TAP(accA[1], p.y,p.z,p.w,pn.x, dA);
        TAP(accA[2], p.z,p.w,pn.x,pn.y, dA); TAP(accA[3], p.w,pn.x,pn.y,pn.z, dA);
        TAP(accB[0], p.x,p.y,p.z,p.w, dB); TAP(accB[1], p.y,p.z,p.w,pn.x, dB);
        TAP(accB[2], p.z,p.w,pn.x,pn.y, dB); TAP(accB[3], p.w,pn.x,pn.y,pn.z, dB);
        p = pn;
    }
    int lt = tid * 4;
    float bvA = -INFINITY, bvB = -INFINITY;
    int biA = 0x7fffffff, biB = 0x7fffffff;
    #pragma unroll
    for (int j = 0; j < 4; j++) {
        int t = tbase + lt + j;
        if (t < TOUT) {
            if (accA[j] > bvA) { bvA = accA[j]; biA = aA*TOUT + t; }
            if (accB[j] > bvB) { bvB = accB[j]; biB = aB*TOUT + t; }
        }
    }
    wave_amax(bvA, biA); wave_amax(bvB, biB);
    if (lane == 0) { sm.wv[w] = bvA; sm.wi[w] = biA; sm.wv[8+w] = bvB; sm.wi[8+w] = biB; }
    __syncthreads();
    if (tid < 4) {
        float v0 = sm.wv[2*tid];   int i0 = sm.wi[2*tid];
        float v1 = sm.wv[2*tid+1]; int i1 = sm.wi[2*tid+1];
        if (v1 > v0 || (v1 == v0 && i1 < i0)) { v0 = v1; i0 = i1; }
        int chunk = c_base + tid;
        if (chunk < NCHUNK) {
            segval[((size_t)b*A + aA)*NCP + chunk] = v0;
            segidx[((size_t)b*A + aA)*NCP + chunk] = i0;
        }
    } else if (tid >= 64 && tid < 68) {
        int c = tid - 64;
        float v0 = sm.wv[8+2*c];   int i0 = sm.wi[8+2*c];
        float v1 = sm.wv[8+2*c+1]; int i1 = sm.wi[8+2*c+1];
        if (v1 > v0 || (v1 == v0 && i1 < i0)) { v0 = v1; i0 = i1; }
        int chunk = c_base + c;
        if (chunk < NCHUNK) {
            segval[((size_t)b*A + aB)*NCP + chunk] = v0;
            segidx[((size_t)b*A + aB)*NCP + chunk] = i0;
        }
    }
    __syncthreads();
    if (w < 2) {   // refresh per-atom best over all chunks
        int at = (w == 0) ? aA : aB;
        float bv = -INFINITY; int bi = 0x7fffffff;
        if (lane < NCHUNK) {
            bv = segval[((size_t)b*A + at)*NCP + lane];
            bi = segidx[((size_t)b*A + at)*NCP + lane];
        }
        wave_amax(bv, bi);
        if (lane == 0) { avn[b*A + at] = bv; ain[b*A + at] = bi; }
    }
}

// ================= cooperative single-kernel path =================
__global__ void __launch_bounds__(BTH, 4)
k_coop(const float* __restrict__ x, const float* __restrict__ d, float* __restrict__ out,
       float* __restrict__ dn, float* __restrict__ rp0, float* __restrict__ rp1,
       float* __restrict__ recon, float* __restrict__ segval, int* __restrict__ segidx,
       float* __restrict__ abv0, int* __restrict__ abi0,
       float* __restrict__ abv1, int* __restrict__ abi1, unsigned* __restrict__ bar) {
    __shared__ Smem sm;
    const int bid = blockIdx.x, tid = threadIdx.x;
    const int a0 = bid & (NBB-1), b = bid >> 7;
    unsigned* bar_b = bar + b*256;          // per-batch counter, 1 KB apart
    unsigned gen = 0;
    dev_norm_init(a0, b, tid, x, d, dn, rp0, recon, sm);
    gen++; gbar(bar_b, gen*NBB);
    dev_conv(a0, b, tid, rp0, dn, segval, segidx, abv0, abi0, sm);
    gen++; gbar(bar_b, gen*NBB);
    const float* rin = rp0; float* rout = rp1;
    const float* avc = abv0; const int* aic = abi0;
    float* avn = abv1; int* ain = abi1;
    for (int it = 0; it < ITERS; it++) {
        dev_iter(a0, b, tid, it == ITERS-1, avc, aic, avn, ain,
                 rin, rout, recon, dn, segval, segidx, sm);
        { const float* t1 = rin; rin = rout; rout = (float*)t1; }
        { const float* t2 = avc; avc = avn; avn = (float*)t2; }
        { const int*   t3 = aic; aic = ain; ain = (int*)t3; }
        gen++; gbar(bar_b, gen*NBB);
    }
    for (int i = a0*BTH + tid; i < T; i += NBB*BTH)
        out[b*T + i] = recon[(size_t)b*TP + PAD + i];
}

// ================= non-cooperative fallback path =================
__global__ void __launch_bounds__(BTH) k_f_norm_init(const float* x, const float* d,
                                                     float* dn, float* rp0, float* recon) {
    __shared__ Smem sm;
    dev_norm_init(blockIdx.x & (NBB-1), blockIdx.x >> 7, threadIdx.x, x, d, dn, rp0, recon, sm);
}
__global__ void __launch_bounds__(BTH, 4) k_f_conv(const float* rp, const float* dn,
                                                   float* segval, int* segidx,
                                                   float* abv, int* abi) {
    __shared__ Smem sm;
    dev_conv(blockIdx.x & (NBB-1), blockIdx.x >> 7, threadIdx.x, rp, dn, segval, segidx, abv, abi, sm);
}
__global__ void __launch_bounds__(BTH, 4) k_f_iter(int last,
                                                   const float* avc, const int* aic,
                                                   float* avn, int* ain,
                                                   const float* rin, float* rout,
                                                   float* recon, const float* dn,
                                                   float* segval, int* segidx) {
    __shared__ Smem sm;
    dev_iter(blockIdx.x & (NBB-1), blockIdx.x >> 7, threadIdx.x, last,
             avc, aic, avn, ain, rin, rout, recon, dn, segval, segidx, sm);
}
__global__ void k_f_out(const float* recon, float* out) {
    int i = blockIdx.x * blockDim.x + threadIdx.x;
    if (i >= B*T) return;
    int b = i / T, t = i - b*T;
    out[i] = recon[(size_t)b*TP + PAD + t];
}

extern "C" void kernel_launch(void* const* d_in, const int* in_sizes, int n_in,
                              void* d_out, int out_size, void* d_ws, size_t ws_size,
                              hipStream_t stream) {
    const float* x = (const float*)d_in[0];
    const float* d = (const float*)d_in[1];
    float* out = (float*)d_out;

    float* ws     = (float*)d_ws;
    float* dn     = ws;                                   // A*K
    float* rp0    = dn  + (size_t)A*K;                    // B*TP
    float* rp1    = rp0 + (size_t)B*TP;                   // B*TP
    float* recon  = rp1 + (size_t)B*TP;                   // B*TP
    float* segval = recon + (size_t)B*TP;                 // B*A*NCP
    int*   segidx = (int*)(segval + (size_t)B*A*NCP);     // B*A*NCP
    float* abv0   = (float*)(segidx + (size_t)B*A*NCP);   // B*A
    float* abv1   = abv0 + (size_t)B*A;                   // B*A
    int*   abi0   = (int*)(abv1 + (size_t)B*A);           // B*A
    int*   abi1   = abi0 + (size_t)B*A;                   // B*A
    unsigned* bar = (unsigned*)(abi1 + (size_t)B*A);      // 4 per-batch counters, 1 KB apart

    // deterministic cooperative-launch feasibility check (host queries only)
    int nb = 0, ncu = 0;
    hipError_t e1 = hipOccupancyMaxActiveBlocksPerMultiprocessor(&nb, (const void*)k_coop, BTH, 0);
    hipError_t e2 = hipDeviceGetAttribute(&ncu, hipDeviceAttributeMultiprocessorCount, 0);
    bool coop = (e1 == hipSuccess && e2 == hipSuccess && nb > 0 && ncu > 0 &&
                 (long)nb * ncu >= NBLK);
    if (coop) {
        hipMemsetAsync(bar, 0, 4*256*sizeof(unsigned), stream);   // zero counters (graph-safe)
        void* args[] = {(void*)&x, (void*)&d, (void*)&out, (void*)&dn,
                        (void*)&rp0, (void*)&rp1, (void*)&recon,
                        (void*)&segval, (void*)&segidx,
                        (void*)&abv0, (void*)&abi0, (void*)&abv1, (void*)&abi1,
                        (void*)&bar};
        hipError_t e = hipLaunchCooperativeKernel((const void*)k_coop, dim3(NBLK), dim3(BTH),
                                                  args, 0, stream);
        if (e == hipSuccess) return;
    }
    // fallback: same device code, separate launches, double-buffered (race-free)
    k_f_norm_init<<<NBLK, BTH, 0, stream>>>(x, d, dn, rp0, recon);
    k_f_conv<<<NBLK, BTH, 0, stream>>>(rp0, dn, segval, segidx, abv0, abi0);
    float* rbuf[2] = {rp0, rp1};
    float* av[2]   = {abv0, abv1};
    int*   ai[2]   = {abi0, abi1};
    for (int it = 0; it < ITERS; it++) {
        k_f_iter<<<NBLK, BTH, 0, stream>>>(it == ITERS-1 ? 1 : 0,
                                           av[it & 1], ai[it & 1],
                                           av[(it + 1) & 1], ai[(it + 1) & 1],
                                           rbuf[it & 1], rbuf[(it + 1) & 1],
                                           recon, dn, segval, segidx);
    }
    k_f_out<<<(B*T + 255)/256, 256, 0, stream>>>(recon, out);
}